// Round 19
// baseline (60.615 us; speedup 1.0000x reference)
//
#include <hip/hip_runtime.h>

#define DEV __device__ __forceinline__

typedef _Float16 h2v __attribute__((ext_vector_type(2)));
typedef _Float16 f16x4v __attribute__((ext_vector_type(4)));
typedef float f32x4v __attribute__((ext_vector_type(4)));

DEV unsigned pk2u(float a, float b) {
    return __builtin_bit_cast(unsigned, __builtin_amdgcn_cvt_pkrtz(a, b));
}
DEV float dot2u(unsigned a, unsigned b, float c) {
#if __has_builtin(__builtin_amdgcn_fdot2)
    return __builtin_amdgcn_fdot2(__builtin_bit_cast(h2v, a),
                                  __builtin_bit_cast(h2v, b), c, false);
#else
    float d;
    asm("v_dot2_f32_f16 %0, %1, %2, %3" : "=v"(d) : "v"(a), "v"(b), "v"(c));
    return d;
#endif
}
DEV f16x4v mk4(unsigned a, unsigned b) {
    union { unsigned u[2]; f16x4v h; } t; t.u[0] = a; t.u[1] = b; return t.h;
}
DEV float hextr(unsigned u, int hi) {
    union { unsigned u; h2v h; } t; t.u = u;
    return (float)t.h[hi];
}

DEV float lrelu(float x, float a) { return x > 0.f ? x : a * x; }
DEV float elu1(float x) { return x > 0.f ? x : (__expf(x) - 1.f); }

// ---- packed fp16 weight workspace layout (u32 offsets) ----
#define OSE 0
#define ODE 512
#define OH1 1536
#define OH2 2560
#define OHO 3584
#define OL1 7680
#define OL2 11136
#define OM1 13184
#define OM2 19840
#define OCO 21888
#define WTOT 22912
#define OHA WTOT          // 64 u32: Ahi1[16] Alo1[16] Ahi2[16] Alo2[16]
#define OCA (WTOT + 64)   // 16 u32
#define WTOT2 (WTOT + 80)
// ---- MFMA A-fragments (tile = 128 u32: [reg 0..1][lane 0..63]) ----
// sigma(group=lane>>4): k = ktile*16 + 4*group + (reg*2 + half)
#define F1 WTOT2            // W_se^T+bias: 4 mt                 -> 512
#define F2 (F1 + 512)       // W_de^T: 2 mt x 4 kt               -> 1024
#define F3 (F2 + 1024)      // Wl1^T+bias: 4 mt x 7 kt           -> 3584
#define F4 (F3 + 3584)      // Wl2^T: 4 mt x 4 kt                -> 2048
#define FM1 (F4 + 2048)     // Wm1^T+bm1(k=205): 4 mt x 13 kt    -> 6656
#define FM2 (FM1 + 6656)    // Wm2^T: 4 mt x 4 kt                -> 2048
#define FHO (FM2 + 2048)    // Who^T: 4 mt x 8 kt                -> 4096
#define FCO2 (FHO + 4096)   // Wco^T: 4 mt x 2 kt                -> 1024
#define FEND2 (FCO2 + 1024)
#define HSH_WS 49152        // hsh f16: 13*16384 rows x 16 u32
#define CV2_WS (HSH_WS + 13 * 16384 * 16)   // cv2 f16: 16384 x 32 u32
#define STG_WS (CV2_WS + 16384 * 32)        // staging: 16384 x 168 u32
#define STG_N 168

__global__ __launch_bounds__(256) void prep_weights(
    const float* __restrict__ W_se, const float* __restrict__ W_de,
    const float* __restrict__ Wh1, const float* __restrict__ Wh2,
    const float* __restrict__ Who, const float* __restrict__ Wl1,
    const float* __restrict__ Wl2, const float* __restrict__ Wm1,
    const float* __restrict__ Wm2, const float* __restrict__ Wco,
    const float* __restrict__ ah1, const float* __restrict__ ah2,
    const float* __restrict__ ac1, const float* __restrict__ ac2,
    const float* __restrict__ Wc1, const float* __restrict__ Wc2,
    const float* __restrict__ b_se, const float* __restrict__ bl1,
    const float* __restrict__ bm1,
    unsigned* __restrict__ ws)
{
    int i = blockIdx.x * 256 + threadIdx.x;
    if (i >= FEND2) return;
    if (i >= WTOT2) {               // MFMA A-fragments
        int i2 = i - WTOT2;
        unsigned val;
        if (i2 < 512) {             // A1: W_se^T, bias in k=15
            int tile = i2 >> 7, rem = i2 & 127, reg = rem >> 6, lane = rem & 63;
            int m = tile * 16 + (lane & 15);
            int k0 = 4 * (lane >> 4) + reg * 2;
            float v0 = (k0 < 15) ? W_se[k0 * 64 + m] : ((k0 == 15) ? b_se[m] : 0.f);
            float v1 = (k0 + 1 < 15) ? W_se[(k0 + 1) * 64 + m] : ((k0 + 1 == 15) ? b_se[m] : 0.f);
            val = pk2u(v0, v1);
        } else if (i2 < 1536) {     // A2: W_de^T
            int j = i2 - 512;
            int tile = j >> 7, rem = j & 127, reg = rem >> 6, lane = rem & 63;
            int mt2 = tile >> 2, kt2 = tile & 3;
            int m = mt2 * 16 + (lane & 15);
            int k0 = kt2 * 16 + 4 * (lane >> 4) + reg * 2;
            val = pk2u(W_de[k0 * 32 + m], W_de[(k0 + 1) * 32 + m]);
        } else if (i2 < 5120) {     // AL1: Wl1^T, bias in k=108
            int j = i2 - 1536;
            int tile = j >> 7, rem = j & 127, reg = rem >> 6, lane = rem & 63;
            int mt1 = tile / 7, kt1 = tile % 7;
            int m = mt1 * 16 + (lane & 15);
            int k0 = kt1 * 16 + 4 * (lane >> 4) + reg * 2;
            float v0 = (k0 < 108) ? Wl1[k0 * 64 + m] : ((k0 == 108) ? bl1[m] : 0.f);
            float v1 = (k0 + 1 < 108) ? Wl1[(k0 + 1) * 64 + m] : ((k0 + 1 == 108) ? bl1[m] : 0.f);
            val = pk2u(v0, v1);
        } else if (i2 < 7168) {     // AL2: Wl2^T
            int j = i2 - 5120;
            int tile = j >> 7, rem = j & 127, reg = rem >> 6, lane = rem & 63;
            int mt1 = tile >> 2, kt1 = tile & 3;
            int m = mt1 * 16 + (lane & 15);
            int k0 = kt1 * 16 + 4 * (lane >> 4) + reg * 2;
            val = pk2u(Wl2[k0 * 64 + m], Wl2[(k0 + 1) * 64 + m]);
        } else if (i2 < 13824) {    // AM1: Wm1^T (K=205), bm1 in k=205
            int j = i2 - 7168;
            int tile = j >> 7, rem = j & 127, reg = rem >> 6, lane = rem & 63;
            int mt1 = tile / 13, kt1 = tile % 13;
            int m = mt1 * 16 + (lane & 15);
            int k0 = kt1 * 16 + 4 * (lane >> 4) + reg * 2;
            float v0 = (k0 < 205) ? Wm1[k0 * 64 + m] : ((k0 == 205) ? bm1[m] : 0.f);
            float v1 = (k0 + 1 < 205) ? Wm1[(k0 + 1) * 64 + m] : ((k0 + 1 == 205) ? bm1[m] : 0.f);
            val = pk2u(v0, v1);
        } else if (i2 < 15872) {    // AM2: Wm2^T
            int j = i2 - 13824;
            int tile = j >> 7, rem = j & 127, reg = rem >> 6, lane = rem & 63;
            int mt1 = tile >> 2, kt1 = tile & 3;
            int m = mt1 * 16 + (lane & 15);
            int k0 = kt1 * 16 + 4 * (lane >> 4) + reg * 2;
            val = pk2u(Wm2[k0 * 64 + m], Wm2[(k0 + 1) * 64 + m]);
        } else if (i2 < 19968) {    // AHO: Who^T (K=128)
            int j = i2 - 15872;
            int tile = j >> 7, rem = j & 127, reg = rem >> 6, lane = rem & 63;
            int mt1 = tile >> 3, kt1 = tile & 7;
            int m = mt1 * 16 + (lane & 15);
            int k0 = kt1 * 16 + 4 * (lane >> 4) + reg * 2;
            val = pk2u(Who[k0 * 64 + m], Who[(k0 + 1) * 64 + m]);
        } else {                    // ACO2: Wco^T (K=32)
            int j = i2 - 19968;
            int tile = j >> 7, rem = j & 127, reg = rem >> 6, lane = rem & 63;
            int mt1 = tile >> 1, kt1 = tile & 1;
            int m = mt1 * 16 + (lane & 15);
            int k0 = kt1 * 16 + 4 * (lane >> 4) + reg * 2;
            val = pk2u(Wco[k0 * 64 + m], Wco[(k0 + 1) * 64 + m]);
        }
        ws[i] = val;
        return;
    }
    if (i >= WTOT) {
        int j = i - WTOT;
        if (j < 64) {               // hdv A-vectors: (Wh @ a_hi/lo), 32-dim
            int vec = j >> 4, c2 = j & 15;
            const float* W = (vec < 2) ? Wh1 : Wh2;
            const float* a = (vec < 2) ? ah1 : ah2;
            int sel = (vec & 1) ? 0 : 64;
            float v0 = 0.f, v1 = 0.f;
            for (int q = 0; q < 64; ++q) {
                v0 += W[(2 * c2) * 64 + q] * a[sel + q];
                v1 += W[(2 * c2 + 1) * 64 + q] * a[sel + q];
            }
            ws[i] = pk2u(v0, v1);
        } else {                    // cav C-vectors
            int jj = j - 64;
            int vec = jj >> 2, p = jj & 3;
            const float* W = (vec < 2) ? Wc1 : Wc2;
            const float* a = (vec < 2) ? ac1 : ac2;
            int sel = (vec & 1) ? 0 : 16;
            int k0 = 2 * p, k1 = 2 * p + 1;
            float v0 = 0.f, v1 = 0.f;
            if (k0 < 6) for (int q = 0; q < 16; ++q) v0 += W[k0 * 16 + q] * a[sel + q];
            if (k1 < 6) for (int q = 0; q < 16; ++q) v1 += W[k1 * 16 + q] * a[sel + q];
            ws[i] = pk2u(v0, v1);
        }
        return;
    }
    const float* W; int K, N, j;
    if (i < ODE)      { W = W_se; K = 15;  N = 64; j = i - OSE; }
    else if (i < OH1) { W = W_de; K = 64;  N = 32; j = i - ODE; }
    else if (i < OH2) { W = Wh1;  K = 32;  N = 64; j = i - OH1; }
    else if (i < OHO) { W = Wh2;  K = 32;  N = 64; j = i - OH2; }
    else if (i < OL1) { W = Who;  K = 128; N = 64; j = i - OHO; }
    else if (i < OL2) { W = Wl1;  K = 108; N = 64; j = i - OL1; }
    else if (i < OM1) { W = Wl2;  K = 64;  N = 64; j = i - OL2; }
    else if (i < OM2) { W = Wm1;  K = 205; N = 64; j = i - OM1; }
    else if (i < OCO) { W = Wm2;  K = 64;  N = 64; j = i - OM2; }
    else              { W = Wco;  K = 32;  N = 64; j = i - OCO; }
    int k2 = j / N, n = j % N;
    float v0 = (2 * k2     < K) ? W[(2 * k2)     * N + n] : 0.f;
    float v1 = (2 * k2 + 1 < K) ? W[(2 * k2 + 1) * N + n] : 0.f;
    ws[i] = pk2u(v0, v1);
}

// Kernel A: MFMA pre-pass (embed 15->64->32 over 13*B rows; lanes MLP over B).
__global__ __launch_bounds__(256) void gemm_pre(
    const float* __restrict__ obs, const unsigned* __restrict__ WS,
    const float* __restrict__ b_de, const float* __restrict__ bl2,
    unsigned* __restrict__ wsh, unsigned* __restrict__ wsc, int split)
{
    const int l = threadIdx.x & 63;
    const int w = threadIdx.x >> 6;
    const int t = blockIdx.x * 4 + w;
    const int lo16 = l & 15, hi4 = l >> 4;

    if (t < split) {
        int g = t * 16 + lo16;
        int e = g / 13, r = g - e * 13;
        const float* o = obs + (size_t)e * 2064;
        unsigned b1[2];
#pragma unroll
        for (int reg = 0; reg < 2; ++reg) {
            float v[2];
#pragma unroll
            for (int h = 0; h < 2; ++h) {
                int k = 4 * hi4 + reg * 2 + h;
                float x;
                if (k < 15) {
                    int tc = k / 3 + 1, ff = k - (k / 3) * 3;
                    int col = (r == 0) ? (234 + ff) : ((r - 1) * 6 + ff);
                    x = o[tc * 344 + col];
                } else x = (k == 15) ? 1.f : 0.f;
                v[h] = x;
            }
            b1[reg] = pk2u(v[0], v[1]);
        }
        f16x4v B1 = mk4(b1[0], b1[1]);
        f32x4v d1[4];
#pragma unroll
        for (int mt = 0; mt < 4; ++mt) {
            f16x4v A = mk4(WS[F1 + mt * 128 + l], WS[F1 + mt * 128 + 64 + l]);
            f32x4v z = {0.f, 0.f, 0.f, 0.f};
            d1[mt] = __builtin_amdgcn_mfma_f32_16x16x16f16(A, B1, z, 0, 0, 0);
        }
        f16x4v B2[4];
#pragma unroll
        for (int kt = 0; kt < 4; ++kt) {
            B2[kt] = mk4(pk2u(lrelu(d1[kt][0], 0.1f), lrelu(d1[kt][1], 0.1f)),
                         pk2u(lrelu(d1[kt][2], 0.1f), lrelu(d1[kt][3], 0.1f)));
        }
#pragma unroll
        for (int mt2 = 0; mt2 < 2; ++mt2) {
            float4 bb = *(const float4*)(b_de + mt2 * 16 + 4 * hi4);
            f32x4v acc = {bb.x, bb.y, bb.z, bb.w};
#pragma unroll
            for (int kt = 0; kt < 4; ++kt) {
                f16x4v A = mk4(WS[F2 + (mt2 * 4 + kt) * 128 + l],
                               WS[F2 + (mt2 * 4 + kt) * 128 + 64 + l]);
                acc = __builtin_amdgcn_mfma_f32_16x16x16f16(A, B2[kt], acc, 0, 0, 0);
            }
            unsigned* dst = wsh + (size_t)g * 16 + mt2 * 8 + 2 * hi4;
            dst[0] = pk2u(acc[0], acc[1]);
            dst[1] = pk2u(acc[2], acc[3]);
        }
    } else {
        int tt = t - split;
        int e = tt * 16 + lo16;
        const float* o = obs + (size_t)e * 2064 + 1840;   // curs[48..]
        f32x4v acc1[4];
#pragma unroll
        for (int mt = 0; mt < 4; ++mt) acc1[mt] = (f32x4v){0.f, 0.f, 0.f, 0.f};
#pragma unroll
        for (int kt = 0; kt < 7; ++kt) {
            unsigned bu[2];
#pragma unroll
            for (int reg = 0; reg < 2; ++reg) {
                float v[2];
#pragma unroll
                for (int h = 0; h < 2; ++h) {
                    int k = kt * 16 + 4 * hi4 + reg * 2 + h;
                    v[h] = (k < 108) ? o[k] : ((k == 108) ? 1.f : 0.f);
                }
                bu[reg] = pk2u(v[0], v[1]);
            }
            f16x4v Bf = mk4(bu[0], bu[1]);
#pragma unroll
            for (int mt = 0; mt < 4; ++mt) {
                f16x4v A = mk4(WS[F3 + (mt * 7 + kt) * 128 + l],
                               WS[F3 + (mt * 7 + kt) * 128 + 64 + l]);
                acc1[mt] = __builtin_amdgcn_mfma_f32_16x16x16f16(A, Bf, acc1[mt], 0, 0, 0);
            }
        }
        f16x4v B2[4];
#pragma unroll
        for (int kt = 0; kt < 4; ++kt) {
            B2[kt] = mk4(pk2u(fmaxf(acc1[kt][0], 0.f), fmaxf(acc1[kt][1], 0.f)),
                         pk2u(fmaxf(acc1[kt][2], 0.f), fmaxf(acc1[kt][3], 0.f)));
        }
#pragma unroll
        for (int mt = 0; mt < 4; ++mt) {
            float4 bb = *(const float4*)(bl2 + mt * 16 + 4 * hi4);
            f32x4v acc = {bb.x, bb.y, bb.z, bb.w};
#pragma unroll
            for (int kt = 0; kt < 4; ++kt) {
                f16x4v A = mk4(WS[F4 + (mt * 4 + kt) * 128 + l],
                               WS[F4 + (mt * 4 + kt) * 128 + 64 + l]);
                acc = __builtin_amdgcn_mfma_f32_16x16x16f16(A, B2[kt], acc, 0, 0, 0);
            }
            unsigned* dst = wsc + (size_t)e * 32 + mt * 8 + 2 * hi4;
            dst[0] = pk2u(fmaxf(acc[0], 0.f), fmaxf(acc[1], 0.f));
            dst[1] = pk2u(fmaxf(acc[2], 0.f), fmaxf(acc[3], 0.f));
        }
    }
}

// Kernel D: output-GAT GEMMs + in-register GAT epilogue + final MLP.
__global__ __launch_bounds__(256) void gemm_final(
    const unsigned* __restrict__ WS, const unsigned* __restrict__ stg,
    const unsigned* __restrict__ wsc,
    const float* __restrict__ aho, const float* __restrict__ aco,
    const float* __restrict__ bm2, float* __restrict__ out)
{
    const int l = threadIdx.x & 63;
    const int w = threadIdx.x >> 6;
    const int t = blockIdx.x * 4 + w;
    const int lo16 = l & 15, hi4 = l >> 4;
    const int e = t * 16 + lo16;
    const unsigned* sv = stg + (size_t)e * STG_N;

    f16x4v Bm[13];

    // ---- hdv output GAT: w0 = x0s@Who, wr = xrs@Who (K=128) ----
    {
        f32x4v a0[4], a1[4];
#pragma unroll
        for (int mt = 0; mt < 4; ++mt) {
            a0[mt] = (f32x4v){0.f, 0.f, 0.f, 0.f};
            a1[mt] = (f32x4v){0.f, 0.f, 0.f, 0.f};
        }
#pragma unroll
        for (int kt = 0; kt < 8; ++kt) {
            f16x4v B0 = mk4(sv[kt * 8 + 2 * hi4], sv[kt * 8 + 2 * hi4 + 1]);
            f16x4v Br = mk4(sv[64 + kt * 8 + 2 * hi4], sv[64 + kt * 8 + 2 * hi4 + 1]);
#pragma unroll
            for (int mt = 0; mt < 4; ++mt) {
                f16x4v A = mk4(WS[FHO + (mt * 8 + kt) * 128 + l],
                               WS[FHO + (mt * 8 + kt) * 128 + 64 + l]);
                a0[mt] = __builtin_amdgcn_mfma_f32_16x16x16f16(A, B0, a0[mt], 0, 0, 0);
                a1[mt] = __builtin_amdgcn_mfma_f32_16x16x16f16(A, Br, a1[mt], 0, 0, 0);
            }
        }
        float si = 0.f, sj = 0.f, sr = 0.f;
#pragma unroll
        for (int mt = 0; mt < 4; ++mt) {
            float4 AL = *(const float4*)(aho + mt * 16 + 4 * hi4);
            float4 AH = *(const float4*)(aho + 64 + mt * 16 + 4 * hi4);
            si += a0[mt][0] * AL.x + a0[mt][1] * AL.y + a0[mt][2] * AL.z + a0[mt][3] * AL.w;
            sj += a0[mt][0] * AH.x + a0[mt][1] * AH.y + a0[mt][2] * AH.z + a0[mt][3] * AH.w;
            sr += a1[mt][0] * AH.x + a1[mt][1] * AH.y + a1[mt][2] * AH.z + a1[mt][3] * AH.w;
        }
        si += __shfl_xor(si, 16); si += __shfl_xor(si, 32);
        sj += __shfl_xor(sj, 16); sj += __shfl_xor(sj, 32);
        sr += __shfl_xor(sr, 16); sr += __shfl_xor(sr, 32);
        float e0 = lrelu(si + sj, 0.2f);
        float er = lrelu(si + sr, 0.2f);
        float m = fmaxf(e0, er);
        float p0 = __expf(e0 - m);
        float pr = __expf(er - m) * 12.f;
        float inv = 1.f / (p0 + pr);
#pragma unroll
        for (int mt = 0; mt < 4; ++mt) {
            float cv[4];
#pragma unroll
            for (int r = 0; r < 4; ++r) {
                float o0 = (p0 * a0[mt][r] + pr * a1[mt][r]) * inv;
                cv[r] = (elu1(o0) + 12.f * elu1(a0[mt][r])) * (1.f / 13.f);
            }
            Bm[mt] = mk4(pk2u(cv[0], cv[1]), pk2u(cv[2], cv[3]));
        }
    }

    // ---- cav output GAT: wc0 = xc0@Wco, wcr = xcr@Wco (K=32) ----
    {
        f32x4v c0[4], c1[4];
#pragma unroll
        for (int mt = 0; mt < 4; ++mt) {
            c0[mt] = (f32x4v){0.f, 0.f, 0.f, 0.f};
            c1[mt] = (f32x4v){0.f, 0.f, 0.f, 0.f};
        }
#pragma unroll
        for (int kt = 0; kt < 2; ++kt) {
            f16x4v B0 = mk4(sv[128 + kt * 8 + 2 * hi4], sv[128 + kt * 8 + 2 * hi4 + 1]);
            f16x4v Br = mk4(sv[144 + kt * 8 + 2 * hi4], sv[144 + kt * 8 + 2 * hi4 + 1]);
#pragma unroll
            for (int mt = 0; mt < 4; ++mt) {
                f16x4v A = mk4(WS[FCO2 + (mt * 2 + kt) * 128 + l],
                               WS[FCO2 + (mt * 2 + kt) * 128 + 64 + l]);
                c0[mt] = __builtin_amdgcn_mfma_f32_16x16x16f16(A, B0, c0[mt], 0, 0, 0);
                c1[mt] = __builtin_amdgcn_mfma_f32_16x16x16f16(A, Br, c1[mt], 0, 0, 0);
            }
        }
        float si = 0.f, sj = 0.f, sr = 0.f;
#pragma unroll
        for (int mt = 0; mt < 4; ++mt) {
            float4 AL = *(const float4*)(aco + mt * 16 + 4 * hi4);
            float4 AH = *(const float4*)(aco + 64 + mt * 16 + 4 * hi4);
            si += c0[mt][0] * AL.x + c0[mt][1] * AL.y + c0[mt][2] * AL.z + c0[mt][3] * AL.w;
            sj += c0[mt][0] * AH.x + c0[mt][1] * AH.y + c0[mt][2] * AH.z + c0[mt][3] * AH.w;
            sr += c1[mt][0] * AH.x + c1[mt][1] * AH.y + c1[mt][2] * AH.z + c1[mt][3] * AH.w;
        }
        si += __shfl_xor(si, 16); si += __shfl_xor(si, 32);
        sj += __shfl_xor(sj, 16); sj += __shfl_xor(sj, 32);
        sr += __shfl_xor(sr, 16); sr += __shfl_xor(sr, 32);
        float e0 = lrelu(si + sj, 0.2f);
        float er = lrelu(si + sr, 0.2f);
        float m = fmaxf(e0, er);
        float p0 = __expf(e0 - m);
        float pr = __expf(er - m) * 8.f;
        float inv = 1.f / (p0 + pr);
#pragma unroll
        for (int mt = 0; mt < 4; ++mt) {
            float cv[4];
#pragma unroll
            for (int r = 0; r < 4; ++r) {
                float o0 = (p0 * c0[mt][r] + pr * c1[mt][r]) * inv;
                cv[r] = (elu1(o0) + 8.f * elu1(c0[mt][r])) * (1.f / 9.f);
            }
            Bm[4 + mt] = mk4(pk2u(cv[0], cv[1]), pk2u(cv[2], cv[3]));
        }
    }

    // ---- cv2 (lanes MLP) + road fragments ----
#pragma unroll
    for (int kt = 8; kt < 12; ++kt)
        Bm[kt] = mk4(wsc[(size_t)e * 32 + (kt - 8) * 8 + 2 * hi4],
                     wsc[(size_t)e * 32 + (kt - 8) * 8 + 2 * hi4 + 1]);
    Bm[12] = mk4(sv[160 + 2 * hi4], sv[160 + 2 * hi4 + 1]);

    // ---- final MLP: 208 -> 64 relu -> 64 relu ----
    f32x4v acc1[4];
#pragma unroll
    for (int mt = 0; mt < 4; ++mt) acc1[mt] = (f32x4v){0.f, 0.f, 0.f, 0.f};
#pragma unroll
    for (int kt = 0; kt < 13; ++kt) {
#pragma unroll
        for (int mt = 0; mt < 4; ++mt) {
            f16x4v A = mk4(WS[FM1 + (mt * 13 + kt) * 128 + l],
                           WS[FM1 + (mt * 13 + kt) * 128 + 64 + l]);
            acc1[mt] = __builtin_amdgcn_mfma_f32_16x16x16f16(A, Bm[kt], acc1[mt], 0, 0, 0);
        }
    }
    f16x4v B2[4];
#pragma unroll
    for (int kt = 0; kt < 4; ++kt) {
        B2[kt] = mk4(pk2u(fmaxf(acc1[kt][0], 0.f), fmaxf(acc1[kt][1], 0.f)),
                     pk2u(fmaxf(acc1[kt][2], 0.f), fmaxf(acc1[kt][3], 0.f)));
    }
#pragma unroll
    for (int mt = 0; mt < 4; ++mt) {
        float4 bb = *(const float4*)(bm2 + mt * 16 + 4 * hi4);
        f32x4v acc = {bb.x, bb.y, bb.z, bb.w};
#pragma unroll
        for (int kt = 0; kt < 4; ++kt) {
            f16x4v A = mk4(WS[FM2 + (mt * 4 + kt) * 128 + l],
                           WS[FM2 + (mt * 4 + kt) * 128 + 64 + l]);
            acc = __builtin_amdgcn_mfma_f32_16x16x16f16(A, B2[kt], acc, 0, 0, 0);
        }
        float4 st;
        st.x = fmaxf(acc[0], 0.f);
        st.y = fmaxf(acc[1], 0.f);
        st.z = fmaxf(acc[2], 0.f);
        st.w = fmaxf(acc[3], 0.f);
        *(float4*)(out + (size_t)e * 64 + mt * 16 + 4 * hi4) = st;
    }
}

// Per-element LDS layout (u32 units), ELEM_U = 1480 (subset used).
#define CURS  624
#define HCF   864
#define SCR   936
#define S12H  1000
#define QCF   1032
#define HCH   1048
#define HSH2  1216
#define ELEM_U 1480

__global__ __launch_bounds__(256, 4) void pred_kernel(
    const float* __restrict__ obs,
    const unsigned* __restrict__ WS,
    const unsigned* __restrict__ WSH,
    const float* __restrict__ Wc1, const float* __restrict__ Wc2,
    unsigned* __restrict__ STG)
{
    const int l = threadIdx.x & 63;
    const int w = threadIdx.x >> 6;
    const int b = blockIdx.x * 4 + w;
    const float* o = obs + (size_t)b * 2064;
    unsigned* stg = STG + (size_t)b * STG_N;

    __shared__ unsigned lds[4 * ELEM_U];
    unsigned* SU = lds + w * ELEM_U;
    float* SF = (float*)SU;

    // ---- phase 0: gather + precomputed loads ----
    for (int i = l; i < 184; i += 64) SF[CURS + i] = o[1792 + i];
    for (int i = l; i < 208; i += 64) {        // hsh: HSH2 half2 only
        int rr = i >> 4, c2 = i & 15;
        SU[HSH2 + rr * 20 + c2] = WSH[(size_t)(b * 13 + rr) * 16 + c2];
    }
    for (int i = l; i < 72; i += 64) {
        int r = i >> 3, f = i & 7;
        float v = 0.f;
        if (f < 6) {
            if (r == 0) {
                int idx = (f < 3) ? (162 + f) : ((f == 3) ? 181 : (175 + f));
                v = SF[CURS + idx];
            } else {
                v = SF[CURS + (r - 1) * 6 + f];
            }
        }
        SF[HCF + i] = v;
    }
    if (l < 36) {
        int r = l >> 2, p = l & 3;
        float v0 = SF[HCF + r * 8 + 2 * p];
        float v1 = SF[HCF + r * 8 + 2 * p + 1];
        SU[HCH + r * 4 + p] = pk2u(v0, v1);
    }

    // ---- phase 3a: all 4 GAT layers' attention scores ----
    {
        int g = l >> 4, r = l & 15;
        float sc = 0.f;
        if (g < 2) {
            if (r < 14) {
                int ridx = (r == 13) ? 0 : r;
                const uint4* hr = (const uint4*)(SU + HSH2 + ridx * 20);
                const uint4* av = (const uint4*)(WS + OHA + g * 32 + ((r == 13) ? 16 : 0));
                uint4 h0 = hr[0], h1 = hr[1], h2 = hr[2], h3 = hr[3];
                uint4 a0 = av[0], a1 = av[1], a2 = av[2], a3 = av[3];
                float sa = 0.f, sb = 0.f;
                sa = dot2u(h0.x, a0.x, sa); sa = dot2u(h0.y, a0.y, sa);
                sa = dot2u(h0.z, a0.z, sa); sa = dot2u(h0.w, a0.w, sa);
                sb = dot2u(h1.x, a1.x, sb); sb = dot2u(h1.y, a1.y, sb);
                sb = dot2u(h1.z, a1.z, sb); sb = dot2u(h1.w, a1.w, sb);
                sa = dot2u(h2.x, a2.x, sa); sa = dot2u(h2.y, a2.y, sa);
                sa = dot2u(h2.z, a2.z, sa); sa = dot2u(h2.w, a2.w, sa);
                sb = dot2u(h3.x, a3.x, sb); sb = dot2u(h3.y, a3.y, sb);
                sb = dot2u(h3.z, a3.z, sb); sb = dot2u(h3.w, a3.w, sb);
                sc = sa + sb;
            }
        } else {
            if (r < 10) {
                int ridx = (r == 9) ? 0 : r;
                const uint4* hr = (const uint4*)(SU + HCH + ridx * 4);
                const uint4* cv = (const uint4*)(WS + OCA + (g - 2) * 8 + ((r == 9) ? 4 : 0));
                uint4 h = hr[0];
                uint4 a = cv[0];
                sc = dot2u(h.x, a.x, sc);
                sc = dot2u(h.y, a.y, sc);
                sc = dot2u(h.z, a.z, sc);
            }
        }
        SF[SCR + l] = sc;
    }

    // ---- phase 3b: softmax + aggregation s-vectors ----
    if (l < 32) {
        const float4* sq = (const float4*)(SF + SCR);
        float4 a0 = sq[0], a1 = sq[1], a2 = sq[2], a3 = sq[3];
        float4 b0 = sq[4], b1 = sq[5], b2 = sq[6], b3 = sq[7];
        float p1[13] = {a0.x,a0.y,a0.z,a0.w,a1.x,a1.y,a1.z,a1.w,a2.x,a2.y,a2.z,a2.w,a3.x};
        float si1 = a3.y;
        float p2[13] = {b0.x,b0.y,b0.z,b0.w,b1.x,b1.y,b1.z,b1.w,b2.x,b2.y,b2.z,b2.w,b3.x};
        float si2 = b3.y;
        float m1 = -1e30f, m2 = -1e30f;
#pragma unroll
        for (int r = 0; r < 13; ++r) {
            p1[r] = lrelu(si1 + p1[r], 0.2f);
            p2[r] = lrelu(si2 + p2[r], 0.2f);
            m1 = fmaxf(m1, p1[r]);
            m2 = fmaxf(m2, p2[r]);
        }
        float den1 = 0.f, den2 = 0.f;
#pragma unroll
        for (int r = 0; r < 13; ++r) {
            p1[r] = __expf(p1[r] - m1);
            p2[r] = __expf(p2[r] - m2);
            den1 += p1[r];
            den2 += p2[r];
        }
        float rd1 = 1.f / den1, rd2 = 1.f / den2;
        int c = l;
        float s1 = 0.f, s2 = 0.f;
#pragma unroll
        for (int r = 0; r < 13; ++r) {
            float h = hextr(SU[HSH2 + r * 20 + (c >> 1)], c & 1);
            s1 = __builtin_fmaf(p1[r], h, s1);
            s2 = __builtin_fmaf(p2[r], h, s2);
        }
        s1 *= rd1; s2 *= rd2;
        float s1n = __shfl_xor(s1, 1), s2n = __shfl_xor(s2, 1);
        if (!(l & 1)) {
            SU[S12H + (c >> 1)] = pk2u(s1, s1n);
            SU[S12H + 16 + (c >> 1)] = pk2u(s2, s2n);
        }
    } else {
        const float4* sq = (const float4*)(SF + SCR + 32);
        float4 a0 = sq[0], a1 = sq[1], a2 = sq[2];
        float4 b0 = sq[4], b1 = sq[5], b2 = sq[6];
        float q1[9] = {a0.x,a0.y,a0.z,a0.w,a1.x,a1.y,a1.z,a1.w,a2.x};
        float sic1 = a2.y;
        float q2[9] = {b0.x,b0.y,b0.z,b0.w,b1.x,b1.y,b1.z,b1.w,b2.x};
        float sic2 = b2.y;
        float m1 = -1e30f, m2 = -1e30f;
#pragma unroll
        for (int r = 0; r < 9; ++r) {
            q1[r] = lrelu(sic1 + q1[r], 0.2f);
            q2[r] = lrelu(sic2 + q2[r], 0.2f);
            m1 = fmaxf(m1, q1[r]);
            m2 = fmaxf(m2, q2[r]);
        }
        float den1 = 0.f, den2 = 0.f;
#pragma unroll
        for (int r = 0; r < 9; ++r) {
            q1[r] = __expf(q1[r] - m1);
            q2[r] = __expf(q2[r] - m2);
            den1 += q1[r];
            den2 += q2[r];
        }
        float rd1 = 1.f / den1, rd2 = 1.f / den2;
        int k = l & 15;
        int gat = (l >> 4) & 1;
        if (k < 6) {
            float su = 0.f;
#pragma unroll
            for (int r = 0; r < 9; ++r) {
                float h = SF[HCF + r * 8 + k];
                su = __builtin_fmaf(gat ? q2[r] : q1[r], h, su);
            }
            su *= gat ? rd2 : rd1;
            SF[QCF + gat * 8 + k] = su;
        }
    }

    // ---- phase 3c: hdv output matvecs -> staging (x0s, xrs) ----
    {
        float o1 = 0.f, w1 = 0.f, o2 = 0.f, w2 = 0.f;
        const uint4* s1v = (const uint4*)(SU + S12H);
        const uint4* s2v = (const uint4*)(SU + S12H + 16);
        const uint4* h0v = (const uint4*)(SU + HSH2);
#pragma unroll
        for (int kc = 0; kc < 4; ++kc) {
            uint4 sa = s1v[kc], sb = s2v[kc], hz = h0v[kc];
            unsigned wa0 = WS[OH1 + (kc * 4 + 0) * 64 + l], wb0 = WS[OH2 + (kc * 4 + 0) * 64 + l];
            unsigned wa1 = WS[OH1 + (kc * 4 + 1) * 64 + l], wb1 = WS[OH2 + (kc * 4 + 1) * 64 + l];
            unsigned wa2 = WS[OH1 + (kc * 4 + 2) * 64 + l], wb2 = WS[OH2 + (kc * 4 + 2) * 64 + l];
            unsigned wa3 = WS[OH1 + (kc * 4 + 3) * 64 + l], wb3 = WS[OH2 + (kc * 4 + 3) * 64 + l];
            o1 = dot2u(sa.x, wa0, o1); o1 = dot2u(sa.y, wa1, o1);
            o1 = dot2u(sa.z, wa2, o1); o1 = dot2u(sa.w, wa3, o1);
            w1 = dot2u(hz.x, wa0, w1); w1 = dot2u(hz.y, wa1, w1);
            w1 = dot2u(hz.z, wa2, w1); w1 = dot2u(hz.w, wa3, w1);
            o2 = dot2u(sb.x, wb0, o2); o2 = dot2u(sb.y, wb1, o2);
            o2 = dot2u(sb.z, wb2, o2); o2 = dot2u(sb.w, wb3, o2);
            w2 = dot2u(hz.x, wb0, w2); w2 = dot2u(hz.y, wb1, w2);
            w2 = dot2u(hz.z, wb2, w2); w2 = dot2u(hz.w, wb3, w2);
        }
        float o1n = __shfl_xor(o1, 1), o2n = __shfl_xor(o2, 1);
        float w1n = __shfl_xor(w1, 1), w2n = __shfl_xor(w2, 1);
        if (!(l & 1)) {
            stg[(l >> 1)] = pk2u(o1, o1n);
            stg[32 + (l >> 1)] = pk2u(o2, o2n);
            stg[64 + (l >> 1)] = pk2u(w1, w1n);
            stg[96 + (l >> 1)] = pk2u(w2, w2n);
        }
    }

    // ---- phase 3d: cav output matvec -> staging (xc0, xcr) ----
    {
        int g = l >> 4, c = l & 15;
        const float* vec = (g & 1) ? (SF + HCF) : (SF + QCF + (g >> 1) * 8);
        const float* Wc = (g < 2) ? Wc1 : Wc2;
        float acc = 0.f;
#pragma unroll
        for (int k = 0; k < 6; ++k)
            acc = __builtin_fmaf(vec[k], Wc[k * 16 + c], acc);
        float an = __shfl_xor(acc, 1);
        if (!(l & 1))
            stg[128 + ((g & 1) ? 16 : 0) + (g >> 1) * 8 + (c >> 1)] = pk2u(acc, an);
    }

    // ---- road gather -> staging[160..168); ch205 = 1 for bm1 fold ----
    {
        float v = 0.f;
        if (l < 13) {
            int idx;
            if (l < 10) {
                int p = l >> 1, odd = l & 1;
                idx = ((p & 1) ? 175 : 156) + (p >> 1) * 2 + odd;
            } else {
                idx = 169 + l;
            }
            v = SF[CURS + idx];
        } else if (l == 13) {
            v = 1.0f;
        }
        float vn = __shfl_xor(v, 1);
        if (l < 16 && !(l & 1)) stg[160 + (l >> 1)] = pk2u(v, vn);
    }
}

extern "C" void kernel_launch(void* const* d_in, const int* in_sizes, int n_in,
                              void* d_out, int out_size, void* d_ws, size_t ws_size,
                              hipStream_t stream) {
    const float* obs  = (const float*)d_in[0];
    const float* W_se = (const float*)d_in[1];
    const float* b_se = (const float*)d_in[2];
    const float* W_de = (const float*)d_in[3];
    const float* b_de = (const float*)d_in[4];
    const float* Wh1  = (const float*)d_in[5];
    const float* ah1  = (const float*)d_in[6];
    const float* Wh2  = (const float*)d_in[7];
    const float* ah2  = (const float*)d_in[8];
    const float* Who  = (const float*)d_in[9];
    const float* aho  = (const float*)d_in[10];
    const float* Wc1  = (const float*)d_in[11];
    const float* ac1  = (const float*)d_in[12];
    const float* Wc2  = (const float*)d_in[13];
    const float* ac2  = (const float*)d_in[14];
    const float* Wco  = (const float*)d_in[15];
    const float* aco  = (const float*)d_in[16];
    const float* Wl1  = (const float*)d_in[17];
    const float* bl1  = (const float*)d_in[18];
    const float* Wl2  = (const float*)d_in[19];
    const float* bl2  = (const float*)d_in[20];
    const float* Wm1  = (const float*)d_in[21];
    const float* bm1  = (const float*)d_in[22];
    const float* Wm2  = (const float*)d_in[23];
    const float* bm2  = (const float*)d_in[24];

    unsigned* ws = (unsigned*)d_ws;
    prep_weights<<<(FEND2 + 255) / 256, 256, 0, stream>>>(
        W_se, W_de, Wh1, Wh2, Who, Wl1, Wl2, Wm1, Wm2, Wco,
        ah1, ah2, ac1, ac2, Wc1, Wc2, b_se, bl1, bm1, ws);

    int B = in_sizes[0] / 2064;  // 16384
    int t1 = (13 * B) / 16;      // 13312 ph1/2 tiles
    int t2 = B / 16;             // 1024 lanes tiles
    gemm_pre<<<(t1 + t2) / 4, 256, 0, stream>>>(
        obs, ws, b_de, bl2, ws + HSH_WS, ws + CV2_WS, t1);

    pred_kernel<<<B / 4, 256, 0, stream>>>(
        obs, ws, ws + HSH_WS, Wc1, Wc2, ws + STG_WS);

    gemm_final<<<(B / 16) / 4, 256, 0, stream>>>(
        ws, ws + STG_WS, ws + CV2_WS, aho, aco, bm2, (float*)d_out);
}

// Round 20
// 59.136 us; speedup vs baseline: 1.0250x; 1.0250x over previous
//
#include <hip/hip_runtime.h>

#define DEV __device__ __forceinline__

typedef _Float16 h2v __attribute__((ext_vector_type(2)));
typedef _Float16 f16x4v __attribute__((ext_vector_type(4)));
typedef float f32x4v __attribute__((ext_vector_type(4)));

DEV unsigned pk2u(float a, float b) {
    return __builtin_bit_cast(unsigned, __builtin_amdgcn_cvt_pkrtz(a, b));
}
DEV float dot2u(unsigned a, unsigned b, float c) {
#if __has_builtin(__builtin_amdgcn_fdot2)
    return __builtin_amdgcn_fdot2(__builtin_bit_cast(h2v, a),
                                  __builtin_bit_cast(h2v, b), c, false);
#else
    float d;
    asm("v_dot2_f32_f16 %0, %1, %2, %3" : "=v"(d) : "v"(a), "v"(b), "v"(c));
    return d;
#endif
}
DEV f16x4v mk4(unsigned a, unsigned b) {
    union { unsigned u[2]; f16x4v h; } t; t.u[0] = a; t.u[1] = b; return t.h;
}

DEV float lrelu(float x, float a) { return x > 0.f ? x : a * x; }
DEV float elu1(float x) { return x > 0.f ? x : (__expf(x) - 1.f); }

// ---- packed fp16 weight workspace layout (u32 offsets) ----
#define OSE 0
#define ODE 512
#define OH1 1536
#define OH2 2560
#define OHO 3584
#define OL1 7680
#define OL2 11136
#define OM1 13184
#define OM2 19840
#define OCO 21888
#define WTOT 22912
#define OHA WTOT          // 64 u32: Ahi1[16] Alo1[16] Ahi2[16] Alo2[16]
#define OCA (WTOT + 64)   // 16 u32
#define WTOT2 (WTOT + 80)
// ---- MFMA A-fragments (tile = 128 u32: [reg 0..1][lane 0..63]) ----
// sigma(group=lane>>4): k = ktile*16 + 4*group + (reg*2 + half)
#define F1 WTOT2            // W_se^T+bias: 4 mt                 -> 512
#define F2 (F1 + 512)       // W_de^T: 2 mt x 4 kt               -> 1024
#define F3 (F2 + 1024)      // Wl1^T+bias: 4 mt x 7 kt           -> 3584
#define F4 (F3 + 3584)      // Wl2^T: 4 mt x 4 kt                -> 2048
#define FM1 (F4 + 2048)     // Wm1^T+bm1(k=205): 4 mt x 13 kt    -> 6656
#define FM2 (FM1 + 6656)    // Wm2^T: 4 mt x 4 kt                -> 2048
#define FHO (FM2 + 2048)    // Who^T: 4 mt x 8 kt                -> 4096
#define FCO2 (FHO + 4096)   // Wco^T: 4 mt x 2 kt                -> 1024
#define FEND2 (FCO2 + 1024)
#define HSH_WS 49152        // hsh f16: 13*16384 rows x 16 u32
#define CV2_WS (HSH_WS + 13 * 16384 * 16)   // cv2 f16: 16384 x 32 u32
#define STG_WS (CV2_WS + 16384 * 32)        // staging: 16384 x 168 u32
#define STG_N 168

__global__ __launch_bounds__(256) void prep_weights(
    const float* __restrict__ W_se, const float* __restrict__ W_de,
    const float* __restrict__ Wh1, const float* __restrict__ Wh2,
    const float* __restrict__ Who, const float* __restrict__ Wl1,
    const float* __restrict__ Wl2, const float* __restrict__ Wm1,
    const float* __restrict__ Wm2, const float* __restrict__ Wco,
    const float* __restrict__ ah1, const float* __restrict__ ah2,
    const float* __restrict__ ac1, const float* __restrict__ ac2,
    const float* __restrict__ Wc1, const float* __restrict__ Wc2,
    const float* __restrict__ b_se, const float* __restrict__ bl1,
    const float* __restrict__ bm1,
    unsigned* __restrict__ ws)
{
    int i = blockIdx.x * 256 + threadIdx.x;
    if (i >= FEND2) return;
    if (i >= WTOT2) {               // MFMA A-fragments
        int i2 = i - WTOT2;
        unsigned val;
        if (i2 < 512) {             // A1: W_se^T, bias in k=15
            int tile = i2 >> 7, rem = i2 & 127, reg = rem >> 6, lane = rem & 63;
            int m = tile * 16 + (lane & 15);
            int k0 = 4 * (lane >> 4) + reg * 2;
            float v0 = (k0 < 15) ? W_se[k0 * 64 + m] : ((k0 == 15) ? b_se[m] : 0.f);
            float v1 = (k0 + 1 < 15) ? W_se[(k0 + 1) * 64 + m] : ((k0 + 1 == 15) ? b_se[m] : 0.f);
            val = pk2u(v0, v1);
        } else if (i2 < 1536) {     // A2: W_de^T
            int j = i2 - 512;
            int tile = j >> 7, rem = j & 127, reg = rem >> 6, lane = rem & 63;
            int mt2 = tile >> 2, kt2 = tile & 3;
            int m = mt2 * 16 + (lane & 15);
            int k0 = kt2 * 16 + 4 * (lane >> 4) + reg * 2;
            val = pk2u(W_de[k0 * 32 + m], W_de[(k0 + 1) * 32 + m]);
        } else if (i2 < 5120) {     // AL1: Wl1^T, bias in k=108
            int j = i2 - 1536;
            int tile = j >> 7, rem = j & 127, reg = rem >> 6, lane = rem & 63;
            int mt1 = tile / 7, kt1 = tile % 7;
            int m = mt1 * 16 + (lane & 15);
            int k0 = kt1 * 16 + 4 * (lane >> 4) + reg * 2;
            float v0 = (k0 < 108) ? Wl1[k0 * 64 + m] : ((k0 == 108) ? bl1[m] : 0.f);
            float v1 = (k0 + 1 < 108) ? Wl1[(k0 + 1) * 64 + m] : ((k0 + 1 == 108) ? bl1[m] : 0.f);
            val = pk2u(v0, v1);
        } else if (i2 < 7168) {     // AL2: Wl2^T
            int j = i2 - 5120;
            int tile = j >> 7, rem = j & 127, reg = rem >> 6, lane = rem & 63;
            int mt1 = tile >> 2, kt1 = tile & 3;
            int m = mt1 * 16 + (lane & 15);
            int k0 = kt1 * 16 + 4 * (lane >> 4) + reg * 2;
            val = pk2u(Wl2[k0 * 64 + m], Wl2[(k0 + 1) * 64 + m]);
        } else if (i2 < 13824) {    // AM1: Wm1^T (K=205), bm1 in k=205
            int j = i2 - 7168;
            int tile = j >> 7, rem = j & 127, reg = rem >> 6, lane = rem & 63;
            int mt1 = tile / 13, kt1 = tile % 13;
            int m = mt1 * 16 + (lane & 15);
            int k0 = kt1 * 16 + 4 * (lane >> 4) + reg * 2;
            float v0 = (k0 < 205) ? Wm1[k0 * 64 + m] : ((k0 == 205) ? bm1[m] : 0.f);
            float v1 = (k0 + 1 < 205) ? Wm1[(k0 + 1) * 64 + m] : ((k0 + 1 == 205) ? bm1[m] : 0.f);
            val = pk2u(v0, v1);
        } else if (i2 < 15872) {    // AM2: Wm2^T
            int j = i2 - 13824;
            int tile = j >> 7, rem = j & 127, reg = rem >> 6, lane = rem & 63;
            int mt1 = tile >> 2, kt1 = tile & 3;
            int m = mt1 * 16 + (lane & 15);
            int k0 = kt1 * 16 + 4 * (lane >> 4) + reg * 2;
            val = pk2u(Wm2[k0 * 64 + m], Wm2[(k0 + 1) * 64 + m]);
        } else if (i2 < 19968) {    // AHO: Who^T (K=128)
            int j = i2 - 15872;
            int tile = j >> 7, rem = j & 127, reg = rem >> 6, lane = rem & 63;
            int mt1 = tile >> 3, kt1 = tile & 7;
            int m = mt1 * 16 + (lane & 15);
            int k0 = kt1 * 16 + 4 * (lane >> 4) + reg * 2;
            val = pk2u(Who[k0 * 64 + m], Who[(k0 + 1) * 64 + m]);
        } else {                    // ACO2: Wco^T (K=32)
            int j = i2 - 19968;
            int tile = j >> 7, rem = j & 127, reg = rem >> 6, lane = rem & 63;
            int mt1 = tile >> 1, kt1 = tile & 1;
            int m = mt1 * 16 + (lane & 15);
            int k0 = kt1 * 16 + 4 * (lane >> 4) + reg * 2;
            val = pk2u(Wco[k0 * 64 + m], Wco[(k0 + 1) * 64 + m]);
        }
        ws[i] = val;
        return;
    }
    if (i >= WTOT) {
        int j = i - WTOT;
        if (j < 64) {               // hdv A-vectors: (Wh @ a_hi/lo), 32-dim
            int vec = j >> 4, c2 = j & 15;
            const float* W = (vec < 2) ? Wh1 : Wh2;
            const float* a = (vec < 2) ? ah1 : ah2;
            int sel = (vec & 1) ? 0 : 64;
            float v0 = 0.f, v1 = 0.f;
            for (int q = 0; q < 64; ++q) {
                v0 += W[(2 * c2) * 64 + q] * a[sel + q];
                v1 += W[(2 * c2 + 1) * 64 + q] * a[sel + q];
            }
            ws[i] = pk2u(v0, v1);
        } else {                    // cav C-vectors
            int jj = j - 64;
            int vec = jj >> 2, p = jj & 3;
            const float* W = (vec < 2) ? Wc1 : Wc2;
            const float* a = (vec < 2) ? ac1 : ac2;
            int sel = (vec & 1) ? 0 : 16;
            int k0 = 2 * p, k1 = 2 * p + 1;
            float v0 = 0.f, v1 = 0.f;
            if (k0 < 6) for (int q = 0; q < 16; ++q) v0 += W[k0 * 16 + q] * a[sel + q];
            if (k1 < 6) for (int q = 0; q < 16; ++q) v1 += W[k1 * 16 + q] * a[sel + q];
            ws[i] = pk2u(v0, v1);
        }
        return;
    }
    const float* W; int K, N, j;
    if (i < ODE)      { W = W_se; K = 15;  N = 64; j = i - OSE; }
    else if (i < OH1) { W = W_de; K = 64;  N = 32; j = i - ODE; }
    else if (i < OH2) { W = Wh1;  K = 32;  N = 64; j = i - OH1; }
    else if (i < OHO) { W = Wh2;  K = 32;  N = 64; j = i - OH2; }
    else if (i < OL1) { W = Who;  K = 128; N = 64; j = i - OHO; }
    else if (i < OL2) { W = Wl1;  K = 108; N = 64; j = i - OL1; }
    else if (i < OM1) { W = Wl2;  K = 64;  N = 64; j = i - OL2; }
    else if (i < OM2) { W = Wm1;  K = 205; N = 64; j = i - OM1; }
    else if (i < OCO) { W = Wm2;  K = 64;  N = 64; j = i - OM2; }
    else              { W = Wco;  K = 32;  N = 64; j = i - OCO; }
    int k2 = j / N, n = j % N;
    float v0 = (2 * k2     < K) ? W[(2 * k2)     * N + n] : 0.f;
    float v1 = (2 * k2 + 1 < K) ? W[(2 * k2 + 1) * N + n] : 0.f;
    ws[i] = pk2u(v0, v1);
}

// Kernel A: MFMA pre-pass (embed 15->64->32 over 13*B rows; lanes MLP over B).
__global__ __launch_bounds__(256) void gemm_pre(
    const float* __restrict__ obs, const unsigned* __restrict__ WS,
    const float* __restrict__ b_de, const float* __restrict__ bl2,
    unsigned* __restrict__ wsh, unsigned* __restrict__ wsc, int split)
{
    const int l = threadIdx.x & 63;
    const int w = threadIdx.x >> 6;
    const int t = blockIdx.x * 4 + w;
    const int lo16 = l & 15, hi4 = l >> 4;

    if (t < split) {
        int g = t * 16 + lo16;
        int e = g / 13, r = g - e * 13;
        const float* o = obs + (size_t)e * 2064;
        unsigned b1[2];
#pragma unroll
        for (int reg = 0; reg < 2; ++reg) {
            float v[2];
#pragma unroll
            for (int h = 0; h < 2; ++h) {
                int k = 4 * hi4 + reg * 2 + h;
                float x;
                if (k < 15) {
                    int tc = k / 3 + 1, ff = k - (k / 3) * 3;
                    int col = (r == 0) ? (234 + ff) : ((r - 1) * 6 + ff);
                    x = o[tc * 344 + col];
                } else x = (k == 15) ? 1.f : 0.f;
                v[h] = x;
            }
            b1[reg] = pk2u(v[0], v[1]);
        }
        f16x4v B1 = mk4(b1[0], b1[1]);
        f32x4v d1[4];
#pragma unroll
        for (int mt = 0; mt < 4; ++mt) {
            f16x4v A = mk4(WS[F1 + mt * 128 + l], WS[F1 + mt * 128 + 64 + l]);
            f32x4v z = {0.f, 0.f, 0.f, 0.f};
            d1[mt] = __builtin_amdgcn_mfma_f32_16x16x16f16(A, B1, z, 0, 0, 0);
        }
        f16x4v B2[4];
#pragma unroll
        for (int kt = 0; kt < 4; ++kt) {
            B2[kt] = mk4(pk2u(lrelu(d1[kt][0], 0.1f), lrelu(d1[kt][1], 0.1f)),
                         pk2u(lrelu(d1[kt][2], 0.1f), lrelu(d1[kt][3], 0.1f)));
        }
#pragma unroll
        for (int mt2 = 0; mt2 < 2; ++mt2) {
            float4 bb = *(const float4*)(b_de + mt2 * 16 + 4 * hi4);
            f32x4v acc = {bb.x, bb.y, bb.z, bb.w};
#pragma unroll
            for (int kt = 0; kt < 4; ++kt) {
                f16x4v A = mk4(WS[F2 + (mt2 * 4 + kt) * 128 + l],
                               WS[F2 + (mt2 * 4 + kt) * 128 + 64 + l]);
                acc = __builtin_amdgcn_mfma_f32_16x16x16f16(A, B2[kt], acc, 0, 0, 0);
            }
            unsigned* dst = wsh + (size_t)g * 16 + mt2 * 8 + 2 * hi4;
            dst[0] = pk2u(acc[0], acc[1]);
            dst[1] = pk2u(acc[2], acc[3]);
        }
    } else {
        int tt = t - split;
        int e = tt * 16 + lo16;
        const float* o = obs + (size_t)e * 2064 + 1840;   // curs[48..]
        f32x4v acc1[4];
#pragma unroll
        for (int mt = 0; mt < 4; ++mt) acc1[mt] = (f32x4v){0.f, 0.f, 0.f, 0.f};
#pragma unroll
        for (int kt = 0; kt < 7; ++kt) {
            unsigned bu[2];
#pragma unroll
            for (int reg = 0; reg < 2; ++reg) {
                float v[2];
#pragma unroll
                for (int h = 0; h < 2; ++h) {
                    int k = kt * 16 + 4 * hi4 + reg * 2 + h;
                    v[h] = (k < 108) ? o[k] : ((k == 108) ? 1.f : 0.f);
                }
                bu[reg] = pk2u(v[0], v[1]);
            }
            f16x4v Bf = mk4(bu[0], bu[1]);
#pragma unroll
            for (int mt = 0; mt < 4; ++mt) {
                f16x4v A = mk4(WS[F3 + (mt * 7 + kt) * 128 + l],
                               WS[F3 + (mt * 7 + kt) * 128 + 64 + l]);
                acc1[mt] = __builtin_amdgcn_mfma_f32_16x16x16f16(A, Bf, acc1[mt], 0, 0, 0);
            }
        }
        f16x4v B2[4];
#pragma unroll
        for (int kt = 0; kt < 4; ++kt) {
            B2[kt] = mk4(pk2u(fmaxf(acc1[kt][0], 0.f), fmaxf(acc1[kt][1], 0.f)),
                         pk2u(fmaxf(acc1[kt][2], 0.f), fmaxf(acc1[kt][3], 0.f)));
        }
#pragma unroll
        for (int mt = 0; mt < 4; ++mt) {
            float4 bb = *(const float4*)(bl2 + mt * 16 + 4 * hi4);
            f32x4v acc = {bb.x, bb.y, bb.z, bb.w};
#pragma unroll
            for (int kt = 0; kt < 4; ++kt) {
                f16x4v A = mk4(WS[F4 + (mt * 4 + kt) * 128 + l],
                               WS[F4 + (mt * 4 + kt) * 128 + 64 + l]);
                acc = __builtin_amdgcn_mfma_f32_16x16x16f16(A, B2[kt], acc, 0, 0, 0);
            }
            unsigned* dst = wsc + (size_t)e * 32 + mt * 8 + 2 * hi4;
            dst[0] = pk2u(fmaxf(acc[0], 0.f), fmaxf(acc[1], 0.f));
            dst[1] = pk2u(fmaxf(acc[2], 0.f), fmaxf(acc[3], 0.f));
        }
    }
}

// Kernel D: output-GAT GEMMs + in-register GAT epilogue + final MLP.
__global__ __launch_bounds__(256) void gemm_final(
    const unsigned* __restrict__ WS, const unsigned* __restrict__ stg,
    const unsigned* __restrict__ wsc,
    const float* __restrict__ aho, const float* __restrict__ aco,
    const float* __restrict__ bm2, float* __restrict__ out)
{
    const int l = threadIdx.x & 63;
    const int w = threadIdx.x >> 6;
    const int t = blockIdx.x * 4 + w;
    const int lo16 = l & 15, hi4 = l >> 4;
    const int e = t * 16 + lo16;
    const unsigned* sv = stg + (size_t)e * STG_N;

    f16x4v Bm[13];

    // ---- hdv output GAT: w0 = x0s@Who, wr = xrs@Who (K=128) ----
    {
        f32x4v a0[4], a1[4];
#pragma unroll
        for (int mt = 0; mt < 4; ++mt) {
            a0[mt] = (f32x4v){0.f, 0.f, 0.f, 0.f};
            a1[mt] = (f32x4v){0.f, 0.f, 0.f, 0.f};
        }
#pragma unroll
        for (int kt = 0; kt < 8; ++kt) {
            f16x4v B0 = mk4(sv[kt * 8 + 2 * hi4], sv[kt * 8 + 2 * hi4 + 1]);
            f16x4v Br = mk4(sv[64 + kt * 8 + 2 * hi4], sv[64 + kt * 8 + 2 * hi4 + 1]);
#pragma unroll
            for (int mt = 0; mt < 4; ++mt) {
                f16x4v A = mk4(WS[FHO + (mt * 8 + kt) * 128 + l],
                               WS[FHO + (mt * 8 + kt) * 128 + 64 + l]);
                a0[mt] = __builtin_amdgcn_mfma_f32_16x16x16f16(A, B0, a0[mt], 0, 0, 0);
                a1[mt] = __builtin_amdgcn_mfma_f32_16x16x16f16(A, Br, a1[mt], 0, 0, 0);
            }
        }
        float si = 0.f, sj = 0.f, sr = 0.f;
#pragma unroll
        for (int mt = 0; mt < 4; ++mt) {
            float4 AL = *(const float4*)(aho + mt * 16 + 4 * hi4);
            float4 AH = *(const float4*)(aho + 64 + mt * 16 + 4 * hi4);
            si += a0[mt][0] * AL.x + a0[mt][1] * AL.y + a0[mt][2] * AL.z + a0[mt][3] * AL.w;
            sj += a0[mt][0] * AH.x + a0[mt][1] * AH.y + a0[mt][2] * AH.z + a0[mt][3] * AH.w;
            sr += a1[mt][0] * AH.x + a1[mt][1] * AH.y + a1[mt][2] * AH.z + a1[mt][3] * AH.w;
        }
        si += __shfl_xor(si, 16); si += __shfl_xor(si, 32);
        sj += __shfl_xor(sj, 16); sj += __shfl_xor(sj, 32);
        sr += __shfl_xor(sr, 16); sr += __shfl_xor(sr, 32);
        float e0 = lrelu(si + sj, 0.2f);
        float er = lrelu(si + sr, 0.2f);
        float m = fmaxf(e0, er);
        float p0 = __expf(e0 - m);
        float pr = __expf(er - m) * 12.f;
        float inv = 1.f / (p0 + pr);
#pragma unroll
        for (int mt = 0; mt < 4; ++mt) {
            float cv[4];
#pragma unroll
            for (int r = 0; r < 4; ++r) {
                float o0 = (p0 * a0[mt][r] + pr * a1[mt][r]) * inv;
                cv[r] = (elu1(o0) + 12.f * elu1(a0[mt][r])) * (1.f / 13.f);
            }
            Bm[mt] = mk4(pk2u(cv[0], cv[1]), pk2u(cv[2], cv[3]));
        }
    }

    // ---- cav output GAT: wc0 = xc0@Wco, wcr = xcr@Wco (K=32) ----
    {
        f32x4v c0[4], c1[4];
#pragma unroll
        for (int mt = 0; mt < 4; ++mt) {
            c0[mt] = (f32x4v){0.f, 0.f, 0.f, 0.f};
            c1[mt] = (f32x4v){0.f, 0.f, 0.f, 0.f};
        }
#pragma unroll
        for (int kt = 0; kt < 2; ++kt) {
            f16x4v B0 = mk4(sv[128 + kt * 8 + 2 * hi4], sv[128 + kt * 8 + 2 * hi4 + 1]);
            f16x4v Br = mk4(sv[144 + kt * 8 + 2 * hi4], sv[144 + kt * 8 + 2 * hi4 + 1]);
#pragma unroll
            for (int mt = 0; mt < 4; ++mt) {
                f16x4v A = mk4(WS[FCO2 + (mt * 2 + kt) * 128 + l],
                               WS[FCO2 + (mt * 2 + kt) * 128 + 64 + l]);
                c0[mt] = __builtin_amdgcn_mfma_f32_16x16x16f16(A, B0, c0[mt], 0, 0, 0);
                c1[mt] = __builtin_amdgcn_mfma_f32_16x16x16f16(A, Br, c1[mt], 0, 0, 0);
            }
        }
        float si = 0.f, sj = 0.f, sr = 0.f;
#pragma unroll
        for (int mt = 0; mt < 4; ++mt) {
            float4 AL = *(const float4*)(aco + mt * 16 + 4 * hi4);
            float4 AH = *(const float4*)(aco + 64 + mt * 16 + 4 * hi4);
            si += c0[mt][0] * AL.x + c0[mt][1] * AL.y + c0[mt][2] * AL.z + c0[mt][3] * AL.w;
            sj += c0[mt][0] * AH.x + c0[mt][1] * AH.y + c0[mt][2] * AH.z + c0[mt][3] * AH.w;
            sr += c1[mt][0] * AH.x + c1[mt][1] * AH.y + c1[mt][2] * AH.z + c1[mt][3] * AH.w;
        }
        si += __shfl_xor(si, 16); si += __shfl_xor(si, 32);
        sj += __shfl_xor(sj, 16); sj += __shfl_xor(sj, 32);
        sr += __shfl_xor(sr, 16); sr += __shfl_xor(sr, 32);
        float e0 = lrelu(si + sj, 0.2f);
        float er = lrelu(si + sr, 0.2f);
        float m = fmaxf(e0, er);
        float p0 = __expf(e0 - m);
        float pr = __expf(er - m) * 8.f;
        float inv = 1.f / (p0 + pr);
#pragma unroll
        for (int mt = 0; mt < 4; ++mt) {
            float cv[4];
#pragma unroll
            for (int r = 0; r < 4; ++r) {
                float o0 = (p0 * c0[mt][r] + pr * c1[mt][r]) * inv;
                cv[r] = (elu1(o0) + 8.f * elu1(c0[mt][r])) * (1.f / 9.f);
            }
            Bm[4 + mt] = mk4(pk2u(cv[0], cv[1]), pk2u(cv[2], cv[3]));
        }
    }

    // ---- cv2 (lanes MLP) + road fragments ----
#pragma unroll
    for (int kt = 8; kt < 12; ++kt)
        Bm[kt] = mk4(wsc[(size_t)e * 32 + (kt - 8) * 8 + 2 * hi4],
                     wsc[(size_t)e * 32 + (kt - 8) * 8 + 2 * hi4 + 1]);
    Bm[12] = mk4(sv[160 + 2 * hi4], sv[160 + 2 * hi4 + 1]);

    // ---- final MLP: 208 -> 64 relu -> 64 relu ----
    f32x4v acc1[4];
#pragma unroll
    for (int mt = 0; mt < 4; ++mt) acc1[mt] = (f32x4v){0.f, 0.f, 0.f, 0.f};
#pragma unroll
    for (int kt = 0; kt < 13; ++kt) {
#pragma unroll
        for (int mt = 0; mt < 4; ++mt) {
            f16x4v A = mk4(WS[FM1 + (mt * 13 + kt) * 128 + l],
                           WS[FM1 + (mt * 13 + kt) * 128 + 64 + l]);
            acc1[mt] = __builtin_amdgcn_mfma_f32_16x16x16f16(A, Bm[kt], acc1[mt], 0, 0, 0);
        }
    }
    f16x4v B2[4];
#pragma unroll
    for (int kt = 0; kt < 4; ++kt) {
        B2[kt] = mk4(pk2u(fmaxf(acc1[kt][0], 0.f), fmaxf(acc1[kt][1], 0.f)),
                     pk2u(fmaxf(acc1[kt][2], 0.f), fmaxf(acc1[kt][3], 0.f)));
    }
#pragma unroll
    for (int mt = 0; mt < 4; ++mt) {
        float4 bb = *(const float4*)(bm2 + mt * 16 + 4 * hi4);
        f32x4v acc = {bb.x, bb.y, bb.z, bb.w};
#pragma unroll
        for (int kt = 0; kt < 4; ++kt) {
            f16x4v A = mk4(WS[FM2 + (mt * 4 + kt) * 128 + l],
                           WS[FM2 + (mt * 4 + kt) * 128 + 64 + l]);
            acc = __builtin_amdgcn_mfma_f32_16x16x16f16(A, B2[kt], acc, 0, 0, 0);
        }
        float4 st;
        st.x = fmaxf(acc[0], 0.f);
        st.y = fmaxf(acc[1], 0.f);
        st.z = fmaxf(acc[2], 0.f);
        st.w = fmaxf(acc[3], 0.f);
        *(float4*)(out + (size_t)e * 64 + mt * 16 + 4 * hi4) = st;
    }
}

// Per-element LDS layout (u32 units), ELEM_U = 1480 (subset used).
// CURS holds COMPACTED curs: [0..48) = curs[0..48), [48..76) = curs[156..184).
#define HSHF  0
#define CURS  624
#define HCF   864
#define SCR   936
#define S12H  1000
#define QCF   1032
#define HCH   1048
#define HSH2  1216
#define ELEM_U 1480

__global__ __launch_bounds__(256, 4) void pred_kernel(
    const float* __restrict__ obs,
    const unsigned* __restrict__ WS,
    const unsigned* __restrict__ WSH,
    const float* __restrict__ Wc1, const float* __restrict__ Wc2,
    unsigned* __restrict__ STG)
{
    const int l = threadIdx.x & 63;
    const int w = threadIdx.x >> 6;
    const int b = blockIdx.x * 4 + w;
    const float* o = obs + (size_t)b * 2064;
    unsigned* stg = STG + (size_t)b * STG_N;

    __shared__ unsigned lds[4 * ELEM_U];
    unsigned* SU = lds + w * ELEM_U;
    float* SF = (float*)SU;

    // ---- phase 0: gather (compacted curs) + precomputed loads ----
    for (int i = l; i < 76; i += 64) {
        int src = (i < 48) ? i : (i + 108);    // [48..76) -> curs[156..184)
        SF[CURS + i] = o[1792 + src];
    }
    for (int i = l; i < 208; i += 64) {        // hsh: HSH2 half2 + HSHF fp32
        int rr = i >> 4, c2 = i & 15;
        unsigned v = WSH[(size_t)(b * 13 + rr) * 16 + c2];
        SU[HSH2 + rr * 20 + c2] = v;
        union { unsigned u; h2v h; } tc; tc.u = v;
        float2 f2; f2.x = (float)tc.h[0]; f2.y = (float)tc.h[1];
        *(float2*)(SF + HSHF + rr * 32 + 2 * c2) = f2;
    }
    for (int i = l; i < 72; i += 64) {
        int r = i >> 3, f = i & 7;
        float v = 0.f;
        if (f < 6) {
            if (r == 0) {
                // orig {162+f, 181, 175+f} -> compacted -108
                int idx = (f < 3) ? (54 + f) : ((f == 3) ? 73 : (67 + f));
                v = SF[CURS + idx];
            } else {
                v = SF[CURS + (r - 1) * 6 + f];
            }
        }
        SF[HCF + i] = v;
    }
    if (l < 36) {
        int r = l >> 2, p = l & 3;
        float v0 = SF[HCF + r * 8 + 2 * p];
        float v1 = SF[HCF + r * 8 + 2 * p + 1];
        SU[HCH + r * 4 + p] = pk2u(v0, v1);
    }

    // ---- phase 3a: all 4 GAT layers' attention scores ----
    {
        int g = l >> 4, r = l & 15;
        float sc = 0.f;
        if (g < 2) {
            if (r < 14) {
                int ridx = (r == 13) ? 0 : r;
                const uint4* hr = (const uint4*)(SU + HSH2 + ridx * 20);
                const uint4* av = (const uint4*)(WS + OHA + g * 32 + ((r == 13) ? 16 : 0));
                uint4 h0 = hr[0], h1 = hr[1], h2 = hr[2], h3 = hr[3];
                uint4 a0 = av[0], a1 = av[1], a2 = av[2], a3 = av[3];
                float sa = 0.f, sb = 0.f;
                sa = dot2u(h0.x, a0.x, sa); sa = dot2u(h0.y, a0.y, sa);
                sa = dot2u(h0.z, a0.z, sa); sa = dot2u(h0.w, a0.w, sa);
                sb = dot2u(h1.x, a1.x, sb); sb = dot2u(h1.y, a1.y, sb);
                sb = dot2u(h1.z, a1.z, sb); sb = dot2u(h1.w, a1.w, sb);
                sa = dot2u(h2.x, a2.x, sa); sa = dot2u(h2.y, a2.y, sa);
                sa = dot2u(h2.z, a2.z, sa); sa = dot2u(h2.w, a2.w, sa);
                sb = dot2u(h3.x, a3.x, sb); sb = dot2u(h3.y, a3.y, sb);
                sb = dot2u(h3.z, a3.z, sb); sb = dot2u(h3.w, a3.w, sb);
                sc = sa + sb;
            }
        } else {
            if (r < 10) {
                int ridx = (r == 9) ? 0 : r;
                const uint4* hr = (const uint4*)(SU + HCH + ridx * 4);
                const uint4* cv = (const uint4*)(WS + OCA + (g - 2) * 8 + ((r == 9) ? 4 : 0));
                uint4 h = hr[0];
                uint4 a = cv[0];
                sc = dot2u(h.x, a.x, sc);
                sc = dot2u(h.y, a.y, sc);
                sc = dot2u(h.z, a.z, sc);
            }
        }
        SF[SCR + l] = sc;
    }

    // ---- phase 3b: softmax + aggregation s-vectors ----
    if (l < 32) {
        const float4* sq = (const float4*)(SF + SCR);
        float4 a0 = sq[0], a1 = sq[1], a2 = sq[2], a3 = sq[3];
        float4 b0 = sq[4], b1 = sq[5], b2 = sq[6], b3 = sq[7];
        float p1[13] = {a0.x,a0.y,a0.z,a0.w,a1.x,a1.y,a1.z,a1.w,a2.x,a2.y,a2.z,a2.w,a3.x};
        float si1 = a3.y;
        float p2[13] = {b0.x,b0.y,b0.z,b0.w,b1.x,b1.y,b1.z,b1.w,b2.x,b2.y,b2.z,b2.w,b3.x};
        float si2 = b3.y;
        float m1 = -1e30f, m2 = -1e30f;
#pragma unroll
        for (int r = 0; r < 13; ++r) {
            p1[r] = lrelu(si1 + p1[r], 0.2f);
            p2[r] = lrelu(si2 + p2[r], 0.2f);
            m1 = fmaxf(m1, p1[r]);
            m2 = fmaxf(m2, p2[r]);
        }
        float den1 = 0.f, den2 = 0.f;
#pragma unroll
        for (int r = 0; r < 13; ++r) {
            p1[r] = __expf(p1[r] - m1);
            p2[r] = __expf(p2[r] - m2);
            den1 += p1[r];
            den2 += p2[r];
        }
        float rd1 = 1.f / den1, rd2 = 1.f / den2;
        int c = l;
        float s1 = 0.f, s2 = 0.f;
#pragma unroll
        for (int r = 0; r < 13; ++r) {
            float h = SF[HSHF + r * 32 + c];
            s1 = __builtin_fmaf(p1[r], h, s1);
            s2 = __builtin_fmaf(p2[r], h, s2);
        }
        s1 *= rd1; s2 *= rd2;
        float s1n = __shfl_xor(s1, 1), s2n = __shfl_xor(s2, 1);
        if (!(l & 1)) {
            SU[S12H + (c >> 1)] = pk2u(s1, s1n);
            SU[S12H + 16 + (c >> 1)] = pk2u(s2, s2n);
        }
    } else {
        const float4* sq = (const float4*)(SF + SCR + 32);
        float4 a0 = sq[0], a1 = sq[1], a2 = sq[2];
        float4 b0 = sq[4], b1 = sq[5], b2 = sq[6];
        float q1[9] = {a0.x,a0.y,a0.z,a0.w,a1.x,a1.y,a1.z,a1.w,a2.x};
        float sic1 = a2.y;
        float q2[9] = {b0.x,b0.y,b0.z,b0.w,b1.x,b1.y,b1.z,b1.w,b2.x};
        float sic2 = b2.y;
        float m1 = -1e30f, m2 = -1e30f;
#pragma unroll
        for (int r = 0; r < 9; ++r) {
            q1[r] = lrelu(sic1 + q1[r], 0.2f);
            q2[r] = lrelu(sic2 + q2[r], 0.2f);
            m1 = fmaxf(m1, q1[r]);
            m2 = fmaxf(m2, q2[r]);
        }
        float den1 = 0.f, den2 = 0.f;
#pragma unroll
        for (int r = 0; r < 9; ++r) {
            q1[r] = __expf(q1[r] - m1);
            q2[r] = __expf(q2[r] - m2);
            den1 += q1[r];
            den2 += q2[r];
        }
        float rd1 = 1.f / den1, rd2 = 1.f / den2;
        int k = l & 15;
        int gat = (l >> 4) & 1;
        if (k < 6) {
            float su = 0.f;
#pragma unroll
            for (int r = 0; r < 9; ++r) {
                float h = SF[HCF + r * 8 + k];
                su = __builtin_fmaf(gat ? q2[r] : q1[r], h, su);
            }
            su *= gat ? rd2 : rd1;
            SF[QCF + gat * 8 + k] = su;
        }
    }

    // ---- phase 3c: hdv output matvecs -> staging (x0s, xrs) ----
    {
        float o1 = 0.f, w1 = 0.f, o2 = 0.f, w2 = 0.f;
        const uint4* s1v = (const uint4*)(SU + S12H);
        const uint4* s2v = (const uint4*)(SU + S12H + 16);
        const uint4* h0v = (const uint4*)(SU + HSH2);
#pragma unroll
        for (int kc = 0; kc < 4; ++kc) {
            uint4 sa = s1v[kc], sb = s2v[kc], hz = h0v[kc];
            unsigned wa0 = WS[OH1 + (kc * 4 + 0) * 64 + l], wb0 = WS[OH2 + (kc * 4 + 0) * 64 + l];
            unsigned wa1 = WS[OH1 + (kc * 4 + 1) * 64 + l], wb1 = WS[OH2 + (kc * 4 + 1) * 64 + l];
            unsigned wa2 = WS[OH1 + (kc * 4 + 2) * 64 + l], wb2 = WS[OH2 + (kc * 4 + 2) * 64 + l];
            unsigned wa3 = WS[OH1 + (kc * 4 + 3) * 64 + l], wb3 = WS[OH2 + (kc * 4 + 3) * 64 + l];
            o1 = dot2u(sa.x, wa0, o1); o1 = dot2u(sa.y, wa1, o1);
            o1 = dot2u(sa.z, wa2, o1); o1 = dot2u(sa.w, wa3, o1);
            w1 = dot2u(hz.x, wa0, w1); w1 = dot2u(hz.y, wa1, w1);
            w1 = dot2u(hz.z, wa2, w1); w1 = dot2u(hz.w, wa3, w1);
            o2 = dot2u(sb.x, wb0, o2); o2 = dot2u(sb.y, wb1, o2);
            o2 = dot2u(sb.z, wb2, o2); o2 = dot2u(sb.w, wb3, o2);
            w2 = dot2u(hz.x, wb0, w2); w2 = dot2u(hz.y, wb1, w2);
            w2 = dot2u(hz.z, wb2, w2); w2 = dot2u(hz.w, wb3, w2);
        }
        float o1n = __shfl_xor(o1, 1), o2n = __shfl_xor(o2, 1);
        float w1n = __shfl_xor(w1, 1), w2n = __shfl_xor(w2, 1);
        if (!(l & 1)) {
            stg[(l >> 1)] = pk2u(o1, o1n);
            stg[32 + (l >> 1)] = pk2u(o2, o2n);
            stg[64 + (l >> 1)] = pk2u(w1, w1n);
            stg[96 + (l >> 1)] = pk2u(w2, w2n);
        }
    }

    // ---- phase 3d: cav output matvec -> staging (xc0, xcr) ----
    {
        int g = l >> 4, c = l & 15;
        const float* vec = (g & 1) ? (SF + HCF) : (SF + QCF + (g >> 1) * 8);
        const float* Wc = (g < 2) ? Wc1 : Wc2;
        float acc = 0.f;
#pragma unroll
        for (int k = 0; k < 6; ++k)
            acc = __builtin_fmaf(vec[k], Wc[k * 16 + c], acc);
        float an = __shfl_xor(acc, 1);
        if (!(l & 1))
            stg[128 + ((g & 1) ? 16 : 0) + (g >> 1) * 8 + (c >> 1)] = pk2u(acc, an);
    }

    // ---- road gather -> staging[160..168); ch205 = 1 for bm1 fold ----
    {
        float v = 0.f;
        if (l < 13) {
            int idx;
            if (l < 10) {
                int p = l >> 1, odd = l & 1;
                idx = ((p & 1) ? 67 : 48) + (p >> 1) * 2 + odd;   // compacted -108
            } else {
                idx = 61 + l;                                      // 179,180,181 - 108
            }
            v = SF[CURS + idx];
        } else if (l == 13) {
            v = 1.0f;
        }
        float vn = __shfl_xor(v, 1);
        if (l < 16 && !(l & 1)) stg[160 + (l >> 1)] = pk2u(v, vn);
    }
}

extern "C" void kernel_launch(void* const* d_in, const int* in_sizes, int n_in,
                              void* d_out, int out_size, void* d_ws, size_t ws_size,
                              hipStream_t stream) {
    const float* obs  = (const float*)d_in[0];
    const float* W_se = (const float*)d_in[1];
    const float* b_se = (const float*)d_in[2];
    const float* W_de = (const float*)d_in[3];
    const float* b_de = (const float*)d_in[4];
    const float* Wh1  = (const float*)d_in[5];
    const float* ah1  = (const float*)d_in[6];
    const float* Wh2  = (const float*)d_in[7];
    const float* ah2  = (const float*)d_in[8];
    const float* Who  = (const float*)d_in[9];
    const float* aho  = (const float*)d_in[10];
    const float* Wc1  = (const float*)d_in[11];
    const float* ac1  = (const float*)d_in[12];
    const float* Wc2  = (const float*)d_in[13];
    const float* ac2  = (const float*)d_in[14];
    const float* Wco  = (const float*)d_in[15];
    const float* aco  = (const float*)d_in[16];
    const float* Wl1  = (const float*)d_in[17];
    const float* bl1  = (const float*)d_in[18];
    const float* Wl2  = (const float*)d_in[19];
    const float* bl2  = (const float*)d_in[20];
    const float* Wm1  = (const float*)d_in[21];
    const float* bm1  = (const float*)d_in[22];
    const float* Wm2  = (const float*)d_in[23];
    const float* bm2  = (const float*)d_in[24];

    unsigned* ws = (unsigned*)d_ws;
    prep_weights<<<(FEND2 + 255) / 256, 256, 0, stream>>>(
        W_se, W_de, Wh1, Wh2, Who, Wl1, Wl2, Wm1, Wm2, Wco,
        ah1, ah2, ac1, ac2, Wc1, Wc2, b_se, bl1, bm1, ws);

    int B = in_sizes[0] / 2064;  // 16384
    int t1 = (13 * B) / 16;      // 13312 ph1/2 tiles
    int t2 = B / 16;             // 1024 lanes tiles
    gemm_pre<<<(t1 + t2) / 4, 256, 0, stream>>>(
        obs, ws, b_de, bl2, ws + HSH_WS, ws + CV2_WS, t1);

    pred_kernel<<<B / 4, 256, 0, stream>>>(
        obs, ws, ws + HSH_WS, Wc1, Wc2, ws + STG_WS);

    gemm_final<<<(B / 16) / 4, 256, 0, stream>>>(
        ws, ws + STG_WS, ws + CV2_WS, aho, aco, bm2, (float*)d_out);
}